// Round 4
// baseline (205.682 us; speedup 1.0000x reference)
//
#include <hip/hip_runtime.h>
#include <hip/hip_bf16.h>

#define NEV 131072
#define NF 128
#define NG 64
#define KIN 192      // NF + NG
#define NH 512
#define NOUT 256     // N_BRANCHES * NF
#define BM 64
#define NTHREADS 512
#define TILES 8
#define NBLK (NEV / (BM * TILES))   // 256

typedef __bf16 bf16x8 __attribute__((ext_vector_type(8)));
typedef __bf16 bf16x4 __attribute__((ext_vector_type(4)));
typedef float f32x4 __attribute__((ext_vector_type(4)));

// Swizzled LDS byte offsets: XOR (row&7)<<4 spreads rows across 16B slots.
__device__ __forceinline__ int a_off(int r, int cb) { return r * 384 + (cb ^ ((r & 7) << 4)); }
__device__ __forceinline__ int h_off(int r, int cb) { return r * 1024 + (cb ^ ((r & 7) << 4)); }

// ---- weight pre-pack into per-wave FRAGMENT ORDER (bf16), 1KB contiguous per
// wave fragment load. Layout identical to round 3 (verified).
__global__ void pack_w(const float* __restrict__ W1, const float* __restrict__ W2,
                       __bf16* __restrict__ w1p, __bf16* __restrict__ w2p) {
    int t = blockIdx.x * blockDim.x + threadIdx.x;
    if (t < KIN * NH) {
        int j = t & 7;
        int lane = (t >> 3) & 63;
        int n = (t >> 9) & 3;
        int r = t >> 11;          // wid*6 + kk
        int kk = r % 6;
        int wid = r / 6;
        int lg = lane >> 4, lr = lane & 15;
        int k = kk * 32 + lg * 8 + j;
        int col = wid * 64 + n * 16 + lr;
        w1p[t] = (__bf16)W1[(size_t)k * NH + col];
    } else {
        int u = t - KIN * NH;
        if (u < NH * NOUT) {
            int j = u & 7;
            int lane = (u >> 3) & 63;
            int n = (u >> 9) & 1;
            int r = u >> 10;      // wid*16 + kk
            int kk = r & 15;
            int wid = r >> 4;
            int lg = lane >> 4, lr = lane & 15;
            int k = kk * 32 + lg * 8 + j;
            int col = wid * 32 + n * 16 + lr;
            w2p[u] = (__bf16)W2[(size_t)k * NOUT + col];
        }
    }
}

template <bool TW>
__global__ __launch_bounds__(NTHREADS, 2) void fused_mlp(
        const float* __restrict__ x, const float* __restrict__ gf,
        const __bf16* __restrict__ w1p, const float* __restrict__ W1f,
        const float* __restrict__ b1,
        const __bf16* __restrict__ w2p, const float* __restrict__ W2f,
        const float* __restrict__ b2,
        const int* __restrict__ idx,
        float* __restrict__ out) {
    __shared__ __align__(16) unsigned char smem[65536];  // A-tile [0,24K) overlaid by h [0,64K)

    const int tid = threadIdx.x;
    const int wid = tid >> 6;          // 0..7
    const int lane = tid & 63;
    const int lg = lane >> 4;          // 0..3
    const int lr = lane & 15;

    const float4* x4 = (const float4*)x;
    const float4* g4 = (const float4*)gf;
    float4* o4 = (float4*)out;

    const int xr = tid >> 5;           // x staging row base (0..15), +16*s
    const int xc = tid & 31;           // x float4 col
    const int gr = tid >> 4;           // gf row base (0..31), +32*s
    const int gc = tid & 15;           // gf float4 col

    float4 xv[4], xs[4], gv[2];        // issue-early staging registers

    auto stage_issue = [&](int row0) {
#pragma unroll
        for (int s = 0; s < 4; ++s) {
            int e = row0 + xr + 16 * s;
            int p = idx[e];
            xv[s] = x4[(size_t)e * 32 + xc];
            xs[s] = xv[s];
            if (p != e) xs[s] = x4[(size_t)p * 32 + xc];   // exec-masked at runtime
        }
#pragma unroll
        for (int s = 0; s < 2; ++s) {
            int e = row0 + gr + 32 * s;
            int p = idx[e] & (NEV - 1);                    // parents_idxs % n_events
            gv[s] = g4[(size_t)p * 16 + gc];
        }
    };
    auto stage_commit = [&](int row0) {
#pragma unroll
        for (int s = 0; s < 4; ++s) {
            int r = xr + 16 * s;
            bf16x4 tb = {(__bf16)xs[s].x, (__bf16)xs[s].y, (__bf16)xs[s].z, (__bf16)xs[s].w};
            *(bf16x4*)(smem + a_off(r, xc * 8)) = tb;
            o4[(size_t)(row0 + r) * 32 + xc] = xv[s];      // out[0:NEV] = x
        }
#pragma unroll
        for (int s = 0; s < 2; ++s) {
            int r = gr + 32 * s;
            bf16x4 tb = {(__bf16)gv[s].x, (__bf16)gv[s].y, (__bf16)gv[s].z, (__bf16)gv[s].w};
            *(bf16x4*)(smem + a_off(r, 256 + gc * 8)) = tb;
        }
    };

    int row0 = blockIdx.x * (BM * TILES);
    stage_issue(row0);
    stage_commit(row0);
    __syncthreads();

    for (int t = 0; t < TILES; ++t) {
        // Launder invariant pointers so weight/bias loads are NOT hoisted out of
        // the tile loop (register-resident weights would blow the VGPR budget).
        const __bf16* w1pt = w1p; const __bf16* w2pt = w2p;
        const float* W1ft = W1f; const float* W2ft = W2f;
        const float* b1t = b1;   const float* b2t = b2;
        asm volatile("" : "+s"(w1pt), "+s"(w2pt), "+s"(b1t), "+s"(b2t), "+s"(W1ft), "+s"(W2ft));

        // --- GEMM1 weight fragments (issue FIRST so stage loads queue behind;
        //     waiting on these does not drain the stage loads)
        bf16x8 b1r[KIN / 32][4];
#pragma unroll
        for (int kk = 0; kk < KIN / 32; ++kk)
#pragma unroll
            for (int n = 0; n < 4; ++n) {
                if (TW) {
                    b1r[kk][n] = *(const bf16x8*)(w1pt + (size_t)(((wid * 6 + kk) * 4 + n) * 64 + lane) * 8);
                } else {
                    int col = wid * 64 + n * 16 + lr;
                    const float* wc = W1ft + (size_t)(kk * 32 + lg * 8) * NH + col;
#pragma unroll
                    for (int i = 0; i < 8; ++i) b1r[kk][n][i] = (__bf16)wc[(size_t)i * NH];
                }
            }

        // --- issue next-tile gather loads (land during GEMM1+epi1+GEMM2)
        if (t + 1 < TILES) stage_issue(row0 + BM);

        // --- GEMM1 (operand-swapped): acc1T[n][m] = h^T fragment.
        // lane holds event e=m*16+lr, hidden cols wid*64+n*16+lg*4+i (consecutive!)
        f32x4 acc1T[4][4] = {};
#pragma unroll
        for (int kk = 0; kk < KIN / 32; ++kk) {
            int kbyte = kk * 64 + lg * 16;
            bf16x8 a[4];
#pragma unroll
            for (int m = 0; m < 4; ++m)
                a[m] = *(const bf16x8*)(smem + a_off(m * 16 + lr, kbyte));
#pragma unroll
            for (int n = 0; n < 4; ++n)
#pragma unroll
                for (int m = 0; m < 4; ++m)
                    acc1T[n][m] = __builtin_amdgcn_mfma_f32_16x16x32_bf16(b1r[kk][n], a[m], acc1T[n][m], 0, 0, 0);
        }

        // --- GEMM2 weight fragments (reuse b1r's registers; live into GEMM2)
        bf16x8 b2r[NH / 32][2];
#pragma unroll
        for (int kk = 0; kk < NH / 32; ++kk)
#pragma unroll
            for (int n = 0; n < 2; ++n) {
                if (TW) {
                    b2r[kk][n] = *(const bf16x8*)(w2pt + (size_t)(((wid * 16 + kk) * 2 + n) * 64 + lane) * 8);
                } else {
                    int col = wid * 32 + n * 16 + lr;
                    const float* wc = W2ft + (size_t)(kk * 32 + lg * 8) * NOUT + col;
#pragma unroll
                    for (int i = 0; i < 8; ++i) b2r[kk][n][i] = (__bf16)wc[(size_t)i * NOUT];
                }
            }

        __syncthreads();   // A(t) fully read

        // --- epi1: bias + leaky_relu -> h bf16 (vectorized ds_write_b64)
#pragma unroll
        for (int n = 0; n < 4; ++n) {
            f32x4 bb = *(const f32x4*)(b1t + wid * 64 + n * 16 + lg * 4);
            int cb = (wid * 64 + n * 16 + lg * 4) * 2;
#pragma unroll
            for (int m = 0; m < 4; ++m) {
                int e = m * 16 + lr;
                bf16x4 tb;
#pragma unroll
                for (int i = 0; i < 4; ++i) {
                    float v = acc1T[n][m][i] + bb[i];
                    v = (v >= 0.f) ? v : 0.01f * v;
                    tb[i] = (__bf16)v;
                }
                *(bf16x4*)(smem + h_off(e, cb)) = tb;
            }
        }
        __syncthreads();   // h ready

        // --- GEMM2 (operand-swapped): lane holds event e=m*16+lr,
        //     out cols wid*32+n*16+lg*4+i (consecutive -> float4 store)
        f32x4 acc2T[2][4] = {};
#pragma unroll
        for (int kk = 0; kk < NH / 32; ++kk) {
            int kbyte = kk * 64 + lg * 16;
            bf16x8 a2[4];
#pragma unroll
            for (int m = 0; m < 4; ++m)
                a2[m] = *(const bf16x8*)(smem + h_off(m * 16 + lr, kbyte));
#pragma unroll
            for (int n = 0; n < 2; ++n)
#pragma unroll
                for (int m = 0; m < 4; ++m)
                    acc2T[n][m] = __builtin_amdgcn_mfma_f32_16x16x32_bf16(b2r[kk][n], a2[m], acc2T[n][m], 0, 0, 0);
        }
        __syncthreads();   // h fully read -> A region free

        // --- write-late: next-tile A into LDS + x out-copy (stores overlap epi2)
        if (t + 1 < TILES) stage_commit(row0 + BM);

        // --- epi2: bias + branch-split float4 stores
#pragma unroll
        for (int n = 0; n < 2; ++n) {
            int f0 = wid * 32 + n * 16 + lg * 4;
            f32x4 bb = *(const f32x4*)(b2t + f0);
            int br = f0 >> 7;
            int f = f0 & 127;
            float* ob = out + ((size_t)NEV * (1 + br)) * NF + f;
#pragma unroll
            for (int m = 0; m < 4; ++m) {
                int e = row0 + m * 16 + lr;
                f32x4 v = acc2T[n][m] + bb;
                *(f32x4*)(ob + (size_t)e * NF) = v;
            }
        }
        __syncthreads();   // A(t+1) in place for next GEMM1
        row0 += BM;
    }
}

extern "C" void kernel_launch(void* const* d_in, const int* in_sizes, int n_in,
                              void* d_out, int out_size, void* d_ws, size_t ws_size,
                              hipStream_t stream) {
    const float* x  = (const float*)d_in[0];
    const float* gf = (const float*)d_in[1];
    const float* W1 = (const float*)d_in[2];
    const float* b1 = (const float*)d_in[3];
    const float* W2 = (const float*)d_in[4];
    const float* b2 = (const float*)d_in[5];
    const int*  idx = (const int*)d_in[6];
    float* out = (float*)d_out;

    const size_t wbytes = (size_t)(KIN * NH + NH * NOUT) * sizeof(__bf16);

    if (ws_size >= wbytes) {
        __bf16* w1p = (__bf16*)d_ws;
        __bf16* w2p = w1p + KIN * NH;
        int tot = KIN * NH + NH * NOUT;
        pack_w<<<(tot + 511) / 512, 512, 0, stream>>>(W1, W2, w1p, w2p);
        fused_mlp<true><<<NBLK, NTHREADS, 0, stream>>>(x, gf, w1p, nullptr, b1,
                                                       w2p, nullptr, b2, idx, out);
    } else {
        fused_mlp<false><<<NBLK, NTHREADS, 0, stream>>>(x, gf, nullptr, W1, b1,
                                                        nullptr, W2, b2, idx, out);
    }
}

// Round 5
// 115.744 us; speedup vs baseline: 1.7770x; 1.7770x over previous
//
#include <hip/hip_runtime.h>
#include <hip/hip_bf16.h>

#define NEV 131072
#define NF 128
#define NG 64
#define KIN 192      // NF + NG
#define NH 512
#define NOUT 256     // N_BRANCHES * NF
#define BM 64
#define NTHREADS 512

typedef __bf16 bf16x8 __attribute__((ext_vector_type(8)));
typedef __bf16 bf16x4 __attribute__((ext_vector_type(4)));
typedef float f32x4 __attribute__((ext_vector_type(4)));

// Swizzled LDS byte offsets: XOR (row&7)<<4 spreads rows across 16B slots.
__device__ __forceinline__ int a_off(int r, int cb) { return r * 384 + (cb ^ ((r & 7) << 4)); }
__device__ __forceinline__ int h_off(int r, int cb) { return r * 1024 + (cb ^ ((r & 7) << 4)); }

// ---- weight pre-pack into per-wave FRAGMENT ORDER (bf16), 1KB contiguous per
// wave fragment load. Layout identical to rounds 3/4 (verified).
__global__ void pack_w(const float* __restrict__ W1, const float* __restrict__ W2,
                       __bf16* __restrict__ w1p, __bf16* __restrict__ w2p) {
    int t = blockIdx.x * blockDim.x + threadIdx.x;
    if (t < KIN * NH) {
        int j = t & 7;
        int lane = (t >> 3) & 63;
        int n = (t >> 9) & 3;
        int r = t >> 11;          // wid*6 + kk
        int kk = r % 6;
        int wid = r / 6;
        int lg = lane >> 4, lr = lane & 15;
        int k = kk * 32 + lg * 8 + j;
        int col = wid * 64 + n * 16 + lr;
        w1p[t] = (__bf16)W1[(size_t)k * NH + col];
    } else {
        int u = t - KIN * NH;
        if (u < NH * NOUT) {
            int j = u & 7;
            int lane = (u >> 3) & 63;
            int n = (u >> 9) & 1;
            int r = u >> 10;      // wid*16 + kk
            int kk = r & 15;
            int wid = r >> 4;
            int lg = lane >> 4, lr = lane & 15;
            int k = kk * 32 + lg * 8 + j;
            int col = wid * 32 + n * 16 + lr;
            w2p[u] = (__bf16)W2[(size_t)k * NOUT + col];
        }
    }
}

template <bool TW>
__global__ __launch_bounds__(NTHREADS, 2) void fused_mlp(
        const float* __restrict__ x, const float* __restrict__ gf,
        const __bf16* __restrict__ w1p, const float* __restrict__ W1f,
        const float* __restrict__ b1,
        const __bf16* __restrict__ w2p, const float* __restrict__ W2f,
        const float* __restrict__ b2,
        const int* __restrict__ idx,
        float* __restrict__ out) {
    __shared__ __align__(16) unsigned char smem[65536];  // A-tile [0,24K), then h [0,64K)

    const int tid = threadIdx.x;
    const int wid = tid >> 6;          // 0..7
    const int lane = tid & 63;
    const int lg = lane >> 4;          // 0..3
    const int lr = lane & 15;
    const int row0 = blockIdx.x * BM;

    // ---- GEMM1 weight fragments (issued first; L2/L3-hot after block 0)
    bf16x8 b1r[KIN / 32][4];
#pragma unroll
    for (int kk = 0; kk < KIN / 32; ++kk)
#pragma unroll
        for (int n = 0; n < 4; ++n) {
            if (TW) {
                b1r[kk][n] = *(const bf16x8*)(w1p + (size_t)(((wid * 6 + kk) * 4 + n) * 64 + lane) * 8);
            } else {
                int col = wid * 64 + n * 16 + lr;
                const float* wc = W1f + (size_t)(kk * 32 + lg * 8) * NH + col;
#pragma unroll
                for (int i = 0; i < 8; ++i) b1r[kk][n][i] = (__bf16)wc[(size_t)i * NH];
            }
        }

    // ---- stage A = [x | gf] bf16 into LDS (swizzled); fused x->out copy (nt)
    const f32x4* x4 = (const f32x4*)x;
    const f32x4* g4 = (const f32x4*)gf;
    f32x4* o4 = (f32x4*)out;
    for (int q = tid; q < BM * (NF / 4); q += NTHREADS) {
        int r = q >> 5, c4 = q & 31;
        int e = row0 + r;
        int p = idx[e];
        f32x4 v = x4[(size_t)e * 32 + c4];
        __builtin_nontemporal_store(v, &o4[(size_t)e * 32 + c4]);   // out[0:NEV] = x
        f32x4 vs = v;
        if (p != e) vs = x4[(size_t)p * 32 + c4];   // exec-masked gather
        bf16x4 tb = {(__bf16)vs[0], (__bf16)vs[1], (__bf16)vs[2], (__bf16)vs[3]};
        *(bf16x4*)(smem + a_off(r, c4 * 8)) = tb;
    }
    for (int q = tid; q < BM * (NG / 4); q += NTHREADS) {
        int r = q >> 4, c4 = q & 15;
        int e = row0 + r;
        int p = idx[e] & (NEV - 1);                 // parents_idxs % n_events
        f32x4 vs = g4[(size_t)p * 16 + c4];
        bf16x4 tb = {(__bf16)vs[0], (__bf16)vs[1], (__bf16)vs[2], (__bf16)vs[3]};
        *(bf16x4*)(smem + a_off(r, 256 + c4 * 8)) = tb;
    }
    __syncthreads();

    // ---- GEMM1 (operand-swapped): acc1T[n][m]; lane holds event e=m*16+lr,
    //      hidden cols wid*64+n*16+lg*4+{0..3} (consecutive per lane)
    f32x4 acc1T[4][4] = {};
#pragma unroll
    for (int kk = 0; kk < KIN / 32; ++kk) {
        int kbyte = kk * 64 + lg * 16;
        bf16x8 a[4];
#pragma unroll
        for (int m = 0; m < 4; ++m)
            a[m] = *(const bf16x8*)(smem + a_off(m * 16 + lr, kbyte));
        __builtin_amdgcn_s_setprio(1);
#pragma unroll
        for (int n = 0; n < 4; ++n)
#pragma unroll
            for (int m = 0; m < 4; ++m)
                acc1T[n][m] = __builtin_amdgcn_mfma_f32_16x16x32_bf16(b1r[kk][n], a[m], acc1T[n][m], 0, 0, 0);
        __builtin_amdgcn_s_setprio(0);
    }

    // ---- GEMM2 weight fragments (issue before barrier; latency hides behind
    //      epi1 + barrier)
    bf16x8 b2r[NH / 32][2];
#pragma unroll
    for (int kk = 0; kk < NH / 32; ++kk)
#pragma unroll
        for (int n = 0; n < 2; ++n) {
            if (TW) {
                b2r[kk][n] = *(const bf16x8*)(w2p + (size_t)(((wid * 16 + kk) * 2 + n) * 64 + lane) * 8);
            } else {
                int col = wid * 32 + n * 16 + lr;
                const float* wc = W2f + (size_t)(kk * 32 + lg * 8) * NOUT + col;
#pragma unroll
                for (int i = 0; i < 8; ++i) b2r[kk][n][i] = (__bf16)wc[(size_t)i * NOUT];
            }
        }

    __syncthreads();   // A fully read; smem becomes h

    // ---- epi1: bias + leaky_relu -> h bf16 (vectorized ds_write_b64)
#pragma unroll
    for (int n = 0; n < 4; ++n) {
        f32x4 bb = *(const f32x4*)(b1 + wid * 64 + n * 16 + lg * 4);
        int cb = (wid * 64 + n * 16 + lg * 4) * 2;
#pragma unroll
        for (int m = 0; m < 4; ++m) {
            int e = m * 16 + lr;
            bf16x4 tb;
#pragma unroll
            for (int i = 0; i < 4; ++i) {
                float v = acc1T[n][m][i] + bb[i];
                v = (v >= 0.f) ? v : 0.01f * v;
                tb[i] = (__bf16)v;
            }
            *(bf16x4*)(smem + h_off(e, cb)) = tb;
        }
    }
    __syncthreads();   // h ready

    // ---- GEMM2 (operand-swapped): lane holds event e=m*16+lr,
    //      out cols wid*32+n*16+lg*4+{0..3} (consecutive -> float4 store)
    f32x4 acc2T[2][4] = {};
#pragma unroll
    for (int kk = 0; kk < NH / 32; ++kk) {
        int kbyte = kk * 64 + lg * 16;
        bf16x8 a2[4];
#pragma unroll
        for (int m = 0; m < 4; ++m)
            a2[m] = *(const bf16x8*)(smem + h_off(m * 16 + lr, kbyte));
        __builtin_amdgcn_s_setprio(1);
#pragma unroll
        for (int n = 0; n < 2; ++n)
#pragma unroll
            for (int m = 0; m < 4; ++m)
                acc2T[n][m] = __builtin_amdgcn_mfma_f32_16x16x32_bf16(b2r[kk][n], a2[m], acc2T[n][m], 0, 0, 0);
        __builtin_amdgcn_s_setprio(0);
    }

    // ---- epi2: bias + branch-split, nt float4 stores, m-outer so both 64B
    //      halves of each 128B out-line issue back-to-back (no RMW window)
    float* ob = out + ((size_t)NEV * (1 + (wid >> 2))) * NF;
#pragma unroll
    for (int m = 0; m < 4; ++m) {
        size_t ebase = (size_t)(row0 + m * 16 + lr) * NF;
#pragma unroll
        for (int n = 0; n < 2; ++n) {
            int col = wid * 32 + n * 16 + lg * 4;
            f32x4 bb = *(const f32x4*)(b2 + col);
            f32x4 v = acc2T[n][m] + bb;
            __builtin_nontemporal_store(v, (f32x4*)(ob + ebase + (col & 127)));
        }
    }
}

extern "C" void kernel_launch(void* const* d_in, const int* in_sizes, int n_in,
                              void* d_out, int out_size, void* d_ws, size_t ws_size,
                              hipStream_t stream) {
    const float* x  = (const float*)d_in[0];
    const float* gf = (const float*)d_in[1];
    const float* W1 = (const float*)d_in[2];
    const float* b1 = (const float*)d_in[3];
    const float* W2 = (const float*)d_in[4];
    const float* b2 = (const float*)d_in[5];
    const int*  idx = (const int*)d_in[6];
    float* out = (float*)d_out;

    const size_t wbytes = (size_t)(KIN * NH + NH * NOUT) * sizeof(__bf16);
    const int nblocks = NEV / BM;

    if (ws_size >= wbytes) {
        __bf16* w1p = (__bf16*)d_ws;
        __bf16* w2p = w1p + KIN * NH;
        int tot = KIN * NH + NH * NOUT;
        pack_w<<<(tot + 511) / 512, 512, 0, stream>>>(W1, W2, w1p, w2p);
        fused_mlp<true><<<nblocks, NTHREADS, 0, stream>>>(x, gf, w1p, nullptr, b1,
                                                          w2p, nullptr, b2, idx, out);
    } else {
        fused_mlp<false><<<nblocks, NTHREADS, 0, stream>>>(x, gf, nullptr, W1, b1,
                                                           nullptr, W2, b2, idx, out);
    }
}